// Round 1
// baseline (113.213 us; speedup 1.0000x reference)
//
#include <hip/hip_runtime.h>

// TemporalPyramidPooling: fused overlapping masked window-means at
// (w,stride) = (4,2), (8,4), (16,8) over x[B=8,T=4096,D=512] fp32.
// Key structure: all windows are unions of non-overlapping timestep PAIRS,
// so each block builds 36 masked pair-sums (64-step tile + 8 halo) in
// registers and emits all three scales from them. x is read ~1.1x, outputs
// written exactly once -> memory-bound, ~130 MB total traffic.

#define EPS 1e-6f

constexpr int B = 8, T = 4096, D = 512;
constexpr int TILE = 64;          // timesteps of output-window starts per block
constexpr int HALO = 8;           // w16 window extends 8 past last start row
constexpr int NT = TILE + HALO;   // 72 timesteps loaded
constexpr int NP = NT / 2;        // 36 pair sums
constexpr int S4 = 2047, S8 = 1023, S16 = 511;

constexpr size_t OFF0 = 0;                           // avg4  [B,S4,D]
constexpr size_t OFF1 = (size_t)B * S4 * D;          // avg8  [B,S8,D]
constexpr size_t OFF2 = OFF1 + (size_t)B * S8 * D;   // avg16 [B,S16,D]
constexpr size_t OFF3 = OFF2 + (size_t)B * S16 * D;  // mask4 [B,S4]
constexpr size_t OFF4 = OFF3 + (size_t)B * S4;       // mask8 [B,S8]
constexpr size_t OFF5 = OFF4 + (size_t)B * S8;       // mask16[B,S16]

__global__ __launch_bounds__(256)
void tpp_kernel(const float* __restrict__ x,
                const int* __restrict__ mask,
                float* __restrict__ out) {
  const int tid  = threadIdx.x;
  const int b    = blockIdx.z;
  const int tile = blockIdx.y;
  const int d    = blockIdx.x * 256 + tid;
  const int t0   = tile * TILE;

  __shared__ float sm[NT];       // per-timestep mask as float
  __shared__ float sc2[NP];      // per-pair valid count
  __shared__ float inv4[TILE / 2];   // 32 reciprocals of clipped counts
  __shared__ float inv8[TILE / 4];   // 16
  __shared__ float inv16[TILE / 8];  // 8

  if (tid < NT) {
    int t = t0 + tid;
    sm[tid] = (t < T && mask[b * T + t] != 0) ? 1.0f : 0.0f;
  }
  __syncthreads();
  if (tid < NP) sc2[tid] = sm[2 * tid] + sm[2 * tid + 1];
  __syncthreads();

  if (tid < 32) {
    float c = sc2[tid] + sc2[tid + 1];
    inv4[tid] = 1.0f / fmaxf(c, EPS);
    if (blockIdx.x == 0) {
      int s = tile * 32 + tid;
      if (s < S4) out[OFF3 + (size_t)b * S4 + s] = (c > 0.f) ? 1.f : 0.f;
    }
  } else if (tid < 48) {
    int k = tid - 32;
    float c = sc2[2 * k] + sc2[2 * k + 1] + sc2[2 * k + 2] + sc2[2 * k + 3];
    inv8[k] = 1.0f / fmaxf(c, EPS);
    if (blockIdx.x == 0) {
      int s = tile * 16 + k;
      if (s < S8) out[OFF4 + (size_t)b * S8 + s] = (c > 0.f) ? 1.f : 0.f;
    }
  } else if (tid < 56) {
    int l = tid - 48;
    float c = 0.f;
#pragma unroll
    for (int i = 0; i < 8; ++i) c += sc2[4 * l + i];
    inv16[l] = 1.0f / fmaxf(c, EPS);
    if (blockIdx.x == 0) {
      int s = tile * 8 + l;
      if (s < S16) out[OFF5 + (size_t)b * S16 + s] = (c > 0.f) ? 1.f : 0.f;
    }
  }
  __syncthreads();

  // 36 masked pair sums for this d-column (coalesced: 256 lanes x 4B rows)
  const float* xb = x + (size_t)b * T * D + d;
  float p[NP];
#pragma unroll
  for (int i = 0; i < NP; ++i) {
    int t = t0 + 2 * i;
    float a0 = 0.f, a1 = 0.f;
    if (t < T) {                       // t even, so t<T implies t+1<T
      a0 = xb[(size_t)t * D];
      a1 = xb[(size_t)(t + 1) * D];
    }
    p[i] = a0 * sm[2 * i] + a1 * sm[2 * i + 1];
  }

  // w=4, stride 2: window = pairs {j, j+1}
  float* o4 = out + OFF0 + ((size_t)b * S4 + (size_t)tile * 32) * D + d;
#pragma unroll
  for (int j = 0; j < 32; ++j) {
    int s = tile * 32 + j;
    if (s < S4) o4[(size_t)j * D] = (p[j] + p[j + 1]) * inv4[j];
  }

  // w=8, stride 4: window = pairs {2k..2k+3}
  float* o8 = out + OFF1 + ((size_t)b * S8 + (size_t)tile * 16) * D + d;
#pragma unroll
  for (int k = 0; k < 16; ++k) {
    int s = tile * 16 + k;
    if (s < S8)
      o8[(size_t)k * D] =
          (p[2 * k] + p[2 * k + 1] + p[2 * k + 2] + p[2 * k + 3]) * inv8[k];
  }

  // w=16, stride 8: window = pairs {4l..4l+7}
  float* o16 = out + OFF2 + ((size_t)b * S16 + (size_t)tile * 8) * D + d;
#pragma unroll
  for (int l = 0; l < 8; ++l) {
    int s = tile * 8 + l;
    if (s < S16) {
      float sum = 0.f;
#pragma unroll
      for (int i = 0; i < 8; ++i) sum += p[4 * l + i];
      o16[(size_t)l * D] = sum * inv16[l];
    }
  }
}

extern "C" void kernel_launch(void* const* d_in, const int* in_sizes, int n_in,
                              void* d_out, int out_size, void* d_ws, size_t ws_size,
                              hipStream_t stream) {
  const float* x   = (const float*)d_in[0];
  const int* mask  = (const int*)d_in[1];
  float* out       = (float*)d_out;
  dim3 grid(D / 256, T / TILE, B);  // (2, 64, 8) = 1024 blocks
  tpp_kernel<<<grid, 256, 0, stream>>>(x, mask, out);
}

// Round 2
// 110.688 us; speedup vs baseline: 1.0228x; 1.0228x over previous
//
#include <hip/hip_runtime.h>

// TemporalPyramidPooling: fused overlapping masked window-means,
// (w,stride) = (4,2), (8,4), (16,8), x[8,4096,512] fp32.
// All windows are unions of non-overlapping timestep PAIRS; each block
// builds 20 masked pair-sums (32-step tile + 8 halo) as float4 in registers
// and emits all three scales. float4 loads/stores (1 KiB per wave-instr),
// guarded path only for the last tile, non-temporal output stores.

#define EPS 1e-6f

typedef float f4 __attribute__((ext_vector_type(4)));

constexpr int B = 8, T = 4096, D = 512, D4 = D / 4;
constexpr int TILE = 32;           // window-start timesteps per block
constexpr int HALO = 8;            // w16 extends 8 past tile
constexpr int NT = TILE + HALO;    // 40 timesteps loaded
constexpr int NP = NT / 2;         // 20 pair sums
constexpr int NTILES = T / TILE;   // 128
constexpr int S4 = 2047, S8 = 1023, S16 = 511;

constexpr size_t OFF0 = 0;                           // avg4  [B,S4,D]
constexpr size_t OFF1 = (size_t)B * S4 * D;          // avg8  [B,S8,D]
constexpr size_t OFF2 = OFF1 + (size_t)B * S8 * D;   // avg16 [B,S16,D]
constexpr size_t OFF3 = OFF2 + (size_t)B * S16 * D;  // mask4 [B,S4]
constexpr size_t OFF4 = OFF3 + (size_t)B * S4;       // mask8 [B,S8]
constexpr size_t OFF5 = OFF4 + (size_t)B * S8;       // mask16[B,S16]

template <bool GUARD>
__device__ __forceinline__ void compute_store(
    const f4* __restrict__ xb,  // x4 + b*T*D4 + tid
    const float* sm, const float* inv4s, const float* inv8s,
    const float* inv16s, float* __restrict__ out, int b, int tile, int tid) {
  const int t0 = tile * TILE;

  f4 p[NP];
#pragma unroll
  for (int i = 0; i < NP; ++i) {
    int t = t0 + 2 * i;
    f4 a0 = {0.f, 0.f, 0.f, 0.f}, a1 = {0.f, 0.f, 0.f, 0.f};
    if (!GUARD || t < T) {  // t even, so t<T implies t+1<T
      a0 = xb[(size_t)t * D4];
      a1 = xb[(size_t)(t + 1) * D4];
    }
    p[i] = a0 * sm[2 * i] + a1 * sm[2 * i + 1];
  }

  // w=4, stride 2: window = pairs {j, j+1}
  f4* o4 = (f4*)(out + OFF0) + ((size_t)b * S4 + (size_t)tile * 16) * D4 + tid;
#pragma unroll
  for (int j = 0; j < 16; ++j) {
    if (!GUARD || (tile * 16 + j) < S4) {
      f4 v = (p[j] + p[j + 1]) * inv4s[j];
      __builtin_nontemporal_store(v, o4 + (size_t)j * D4);
    }
  }

  // w=8, stride 4: window = pairs {2k..2k+3}
  f4* o8 = (f4*)(out + OFF1) + ((size_t)b * S8 + (size_t)tile * 8) * D4 + tid;
#pragma unroll
  for (int k = 0; k < 8; ++k) {
    if (!GUARD || (tile * 8 + k) < S8) {
      f4 v = (p[2 * k] + p[2 * k + 1] + p[2 * k + 2] + p[2 * k + 3]) * inv8s[k];
      __builtin_nontemporal_store(v, o8 + (size_t)k * D4);
    }
  }

  // w=16, stride 8: window = pairs {4l..4l+7}
  f4* o16 =
      (f4*)(out + OFF2) + ((size_t)b * S16 + (size_t)tile * 4) * D4 + tid;
#pragma unroll
  for (int l = 0; l < 4; ++l) {
    if (!GUARD || (tile * 4 + l) < S16) {
      f4 v = {0.f, 0.f, 0.f, 0.f};
#pragma unroll
      for (int i = 0; i < 8; ++i) v += p[4 * l + i];
      v *= inv16s[l];
      __builtin_nontemporal_store(v, o16 + (size_t)l * D4);
    }
  }
}

__global__ __launch_bounds__(128)
void tpp_kernel(const f4* __restrict__ x4, const int* __restrict__ mask,
                float* __restrict__ out) {
  const int tid = threadIdx.x;  // d4 lane, 0..127
  const int b = blockIdx.z;
  const int tile = blockIdx.y;
  const int t0 = tile * TILE;

  __shared__ float sm[NT];
  __shared__ float sc2[NP];
  __shared__ float inv4s[16], inv8s[8], inv16s[4];

  if (tid < NT) {
    int t = t0 + tid;
    sm[tid] = (t < T && mask[b * T + t] != 0) ? 1.0f : 0.0f;
  }
  __syncthreads();
  if (tid < NP) sc2[tid] = sm[2 * tid] + sm[2 * tid + 1];
  __syncthreads();

  if (tid < 16) {
    float c = sc2[tid] + sc2[tid + 1];
    inv4s[tid] = 1.0f / fmaxf(c, EPS);
    int s = tile * 16 + tid;
    if (s < S4) out[OFF3 + (size_t)b * S4 + s] = (c > 0.f) ? 1.f : 0.f;
  } else if (tid < 24) {
    int k = tid - 16;
    float c = sc2[2 * k] + sc2[2 * k + 1] + sc2[2 * k + 2] + sc2[2 * k + 3];
    inv8s[k] = 1.0f / fmaxf(c, EPS);
    int s = tile * 8 + k;
    if (s < S8) out[OFF4 + (size_t)b * S8 + s] = (c > 0.f) ? 1.f : 0.f;
  } else if (tid < 28) {
    int l = tid - 24;
    float c = 0.f;
#pragma unroll
    for (int i = 0; i < 8; ++i) c += sc2[4 * l + i];
    inv16s[l] = 1.0f / fmaxf(c, EPS);
    int s = tile * 4 + l;
    if (s < S16) out[OFF5 + (size_t)b * S16 + s] = (c > 0.f) ? 1.f : 0.f;
  }
  __syncthreads();

  const f4* xb = x4 + (size_t)b * T * D4 + tid;
  if (tile < NTILES - 1)
    compute_store<false>(xb, sm, inv4s, inv8s, inv16s, out, b, tile, tid);
  else
    compute_store<true>(xb, sm, inv4s, inv8s, inv16s, out, b, tile, tid);
}

extern "C" void kernel_launch(void* const* d_in, const int* in_sizes, int n_in,
                              void* d_out, int out_size, void* d_ws,
                              size_t ws_size, hipStream_t stream) {
  const f4* x4 = (const f4*)d_in[0];
  const int* mask = (const int*)d_in[1];
  float* out = (float*)d_out;
  dim3 grid(1, NTILES, B);  // (1,128,8) = 1024 blocks
  tpp_kernel<<<grid, 128, 0, stream>>>(x4, mask, out);
}

// Round 3
// 109.443 us; speedup vs baseline: 1.0345x; 1.0114x over previous
//
#include <hip/hip_runtime.h>

// TemporalPyramidPooling: fused overlapping masked window-means,
// (w,stride) = (4,2), (8,4), (16,8), x[8,4096,512] fp32.
// R3: barrier-free, LDS-free. Mask ints are wave-uniform per tile -> scalar
// loads + in-register count/reciprocal tree. Single-wave blocks (64 threads
// = half of D4), grid (2,128,8). Pair-sum reuse: q4 -> sum8 -> sum16.

#define EPS 1e-6f

typedef float f4 __attribute__((ext_vector_type(4)));

constexpr int B = 8, T = 4096, D = 512, D4 = D / 4;
constexpr int TILE = 32;          // window-start timesteps per block
constexpr int HALO = 8;           // w16 extends 8 past tile
constexpr int NT = TILE + HALO;   // 40 timesteps
constexpr int NP = NT / 2;        // 20 pair sums
constexpr int NTILES = T / TILE;  // 128
constexpr int S4 = 2047, S8 = 1023, S16 = 511;

constexpr size_t OFF0 = 0;                           // avg4  [B,S4,D]
constexpr size_t OFF1 = (size_t)B * S4 * D;          // avg8  [B,S8,D]
constexpr size_t OFF2 = OFF1 + (size_t)B * S8 * D;   // avg16 [B,S16,D]
constexpr size_t OFF3 = OFF2 + (size_t)B * S16 * D;  // mask4 [B,S4]
constexpr size_t OFF4 = OFF3 + (size_t)B * S4;       // mask8 [B,S8]
constexpr size_t OFF5 = OFF4 + (size_t)B * S8;       // mask16[B,S16]

template <bool GUARD>
__device__ __forceinline__ void tile_body(const f4* __restrict__ x4,
                                          const int* __restrict__ mask,
                                          float* __restrict__ out, int b,
                                          int tile, int d4, int lane,
                                          bool write_masks) {
  const int t0 = tile * TILE;

  // ---- wave-uniform mask: scalar loads + in-register float conversion ----
  const int* mp = mask + (size_t)b * T + t0;
  float mf[NT];
#pragma unroll
  for (int i = 0; i < NT; ++i) {
    int m = (!GUARD || (t0 + i) < T) ? mp[i] : 0;
    mf[i] = (m != 0) ? 1.0f : 0.0f;
  }

  // count tree (all wave-uniform)
  float c2[NP];
#pragma unroll
  for (int i = 0; i < NP; ++i) c2[i] = mf[2 * i] + mf[2 * i + 1];
  float c4[19];  // c4[j] = pairs {j,j+1}, j=0..18
#pragma unroll
  for (int j = 0; j < 19; ++j) c4[j] = c2[j] + c2[j + 1];
  float c8[9];  // c8[k] = pairs {2k..2k+3} = c4[2k]+c4[2k+2]
#pragma unroll
  for (int k = 0; k < 9; ++k) c8[k] = c4[2 * k] + c4[2 * k + 2];
  float c16[4];  // c16[l] = pairs {4l..4l+7} = c8[2l]+c8[2l+2]
#pragma unroll
  for (int l = 0; l < 4; ++l) c16[l] = c8[2 * l] + c8[2 * l + 2];

  float i4[16], i8[8], i16[4];
#pragma unroll
  for (int j = 0; j < 16; ++j) i4[j] = 1.0f / fmaxf(c4[j], EPS);
#pragma unroll
  for (int k = 0; k < 8; ++k) i8[k] = 1.0f / fmaxf(c8[k], EPS);
#pragma unroll
  for (int l = 0; l < 4; ++l) i16[l] = 1.0f / fmaxf(c16[l], EPS);

  // ---- mask outputs (one wave per (b,tile): blockIdx.x==0), lane-select ----
  if (write_masks) {
    if (lane < 16) {
      int s = tile * 16 + lane;
      if (!GUARD || s < S4) {
        float c = 0.f;
#pragma unroll
        for (int j = 0; j < 16; ++j) c = (lane == j) ? c4[j] : c;
        out[OFF3 + (size_t)b * S4 + s] = (c > 0.f) ? 1.f : 0.f;
      }
    } else if (lane < 24) {
      int k = lane - 16, s = tile * 8 + k;
      if (!GUARD || s < S8) {
        float c = 0.f;
#pragma unroll
        for (int j = 0; j < 8; ++j) c = (k == j) ? c8[j] : c;
        out[OFF4 + (size_t)b * S8 + s] = (c > 0.f) ? 1.f : 0.f;
      }
    } else if (lane < 28) {
      int l = lane - 24, s = tile * 4 + l;
      if (!GUARD || s < S16) {
        float c = 0.f;
#pragma unroll
        for (int j = 0; j < 4; ++j) c = (l == j) ? c16[j] : c;
        out[OFF5 + (size_t)b * S16 + s] = (c > 0.f) ? 1.f : 0.f;
      }
    }
  }

  // ---- masked pair sums for this d4 column ----
  const f4* xb = x4 + (size_t)b * T * D4 + d4;
  f4 p[NP];
#pragma unroll
  for (int i = 0; i < NP; ++i) {
    int t = t0 + 2 * i;
    f4 a0 = {0.f, 0.f, 0.f, 0.f}, a1 = {0.f, 0.f, 0.f, 0.f};
    if (!GUARD || t < T) {  // t even: t<T implies t+1<T
      a0 = xb[(size_t)t * D4];
      a1 = xb[(size_t)(t + 1) * D4];
    }
    p[i] = a0 * mf[2 * i] + a1 * mf[2 * i + 1];
  }

  // value sum tree (mirrors count tree)
  f4 q4[19];
#pragma unroll
  for (int j = 0; j < 19; ++j) q4[j] = p[j] + p[j + 1];
  f4 q8[9];
#pragma unroll
  for (int k = 0; k < 9; ++k) q8[k] = q4[2 * k] + q4[2 * k + 2];

  // w=4 outputs
  f4* o4 = (f4*)(out + OFF0) + ((size_t)b * S4 + (size_t)tile * 16) * D4 + d4;
#pragma unroll
  for (int j = 0; j < 16; ++j) {
    if (!GUARD || (tile * 16 + j) < S4) {
      f4 v = q4[j] * i4[j];
      __builtin_nontemporal_store(v, o4 + (size_t)j * D4);
    }
  }

  // w=8 outputs
  f4* o8 = (f4*)(out + OFF1) + ((size_t)b * S8 + (size_t)tile * 8) * D4 + d4;
#pragma unroll
  for (int k = 0; k < 8; ++k) {
    if (!GUARD || (tile * 8 + k) < S8) {
      f4 v = q8[k] * i8[k];
      __builtin_nontemporal_store(v, o8 + (size_t)k * D4);
    }
  }

  // w=16 outputs
  f4* o16 = (f4*)(out + OFF2) + ((size_t)b * S16 + (size_t)tile * 4) * D4 + d4;
#pragma unroll
  for (int l = 0; l < 4; ++l) {
    if (!GUARD || (tile * 4 + l) < S16) {
      f4 v = (q8[2 * l] + q8[2 * l + 2]) * i16[l];
      __builtin_nontemporal_store(v, o16 + (size_t)l * D4);
    }
  }
}

__global__ __launch_bounds__(64)
void tpp_kernel(const f4* __restrict__ x4, const int* __restrict__ mask,
                float* __restrict__ out) {
  const int lane = threadIdx.x;               // 0..63
  const int d4 = blockIdx.x * 64 + lane;      // 0..127
  const int b = blockIdx.z;
  const int tile = blockIdx.y;
  const bool write_masks = (blockIdx.x == 0);

  if (tile < NTILES - 1)
    tile_body<false>(x4, mask, out, b, tile, d4, lane, write_masks);
  else
    tile_body<true>(x4, mask, out, b, tile, d4, lane, write_masks);
}

extern "C" void kernel_launch(void* const* d_in, const int* in_sizes, int n_in,
                              void* d_out, int out_size, void* d_ws,
                              size_t ws_size, hipStream_t stream) {
  const f4* x4 = (const f4*)d_in[0];
  const int* mask = (const int*)d_in[1];
  float* out = (float*)d_out;
  dim3 grid(D4 / 64, NTILES, B);  // (2,128,8) = 2048 single-wave blocks
  tpp_kernel<<<grid, 64, 0, stream>>>(x4, mask, out);
}